// Round 2
// baseline (329.762 us; speedup 1.0000x reference)
//
#include <hip/hip_runtime.h>
#include <math.h>

#define NR 7
#define ED 128
#define NUND 500000

// d_ws float layout:
// [0, 896)     M[d*7+k]   = sum_j gamma[j]*Wsw[d,j]*W12[j,k]
// [896, 1024)  wsum[d]    = sum_j gamma[j]*Wsw[d,j]
// [1024, 1152) bb[d]      = sum_j beta[j]*Wsw[d,j]
// [1152, 1201) Q[k*7+k2]  = sum_j W12[j,k]*W12[j,k2]
// [1201, 1208) m12[k]     = mean_j W12[j,k]

__global__ __launch_bounds__(128) void precompute_kernel(
    const float* __restrict__ W1, const float* __restrict__ W2,
    const float* __restrict__ gamma, const float* __restrict__ beta,
    const float* __restrict__ Wsw, float* __restrict__ ws)
{
  __shared__ float sW12[ED][NR];
  const int d = threadIdx.x;  // 0..127
  float w12[NR];
#pragma unroll
  for (int k = 0; k < NR; ++k) w12[k] = 0.f;
  for (int j = 0; j < ED; ++j) {
    float w2 = W2[d * ED + j];
#pragma unroll
    for (int k = 0; k < NR; ++k) w12[k] = fmaf(w2, W1[j * NR + k], w12[k]);
  }
#pragma unroll
  for (int k = 0; k < NR; ++k) sW12[d][k] = w12[k];
  __syncthreads();

  float m[NR];
#pragma unroll
  for (int k = 0; k < NR; ++k) m[k] = 0.f;
  float wsum = 0.f, bb = 0.f;
  for (int j = 0; j < ED; ++j) {
    float wv = Wsw[d * ED + j];
    float wg = wv * gamma[j];
    wsum += wg;
    bb = fmaf(wv, beta[j], bb);
#pragma unroll
    for (int k = 0; k < NR; ++k) m[k] = fmaf(wg, sW12[j][k], m[k]);
  }
#pragma unroll
  for (int k = 0; k < NR; ++k) ws[d * NR + k] = m[k];
  ws[896 + d] = wsum;
  ws[1024 + d] = bb;

  if (d < 49) {
    int k = d / 7, k2 = d % 7;
    float q = 0.f;
    for (int j = 0; j < ED; ++j) q = fmaf(sW12[j][k], sW12[j][k2], q);
    ws[1152 + d] = q;
  } else if (d < 56) {
    int k = d - 49;
    float s = 0.f;
    for (int j = 0; j < ED; ++j) s += sW12[j][k];
    ws[1201 + k] = s * (1.f / 128.f);
  }
}

__global__ __launch_bounds__(256) void edge_kernel(
    const float* __restrict__ el, const int* __restrict__ u2d,
    const float* __restrict__ ws, float* __restrict__ out)
{
  __shared__ float sQ[56];          // Q[49] then m12[7]
  __shared__ float sA[256][8];      // per-edge: rbf*rs [7], mu*rs
  const int t = threadIdx.x;

  if (t < 56) sQ[t] = ws[1152 + t];

  // Phase-B per-thread weights: lane group of 32 covers all 128 features,
  // each lane owns 4 consecutive d's.
  const int l = t & 31;   // lane within feature-group
  const int g = t >> 5;   // edge-subgroup 0..7
  float M4[4][NR], ws4[4], bb4[4];
#pragma unroll
  for (int c = 0; c < 4; ++c) {
    int d = 4 * l + c;
#pragma unroll
    for (int k = 0; k < NR; ++k) M4[c][k] = ws[d * NR + k];
    ws4[c] = ws[896 + d];
    bb4[c] = ws[1024 + d];
  }

  const int u0 = blockIdx.x * 256;
  const int u  = u0 + t;
  __syncthreads();  // sQ ready

  if (u < NUND) {
    const float r = el[u2d[u]];
    const float invr = 1.f / r;
    const float PI = 3.14159265358979323846f;

    // pairwise RBF, cutoff 6
    float rb[NR];
    {
      float x = r * (1.f / 6.f);
      float x2 = x * x, x4 = x2 * x2, x8 = x4 * x4;
      float env = fmaf(x8, fmaf(x, fmaf(x, -36.f, 80.f), -45.f), 1.f);
      if (x >= 1.f) env = 0.f;
      float sc = 0.57735026918962576f * env * invr;  // sqrt(2/6)
      float a = PI * x;
      float s1, c1;
      __sincosf(a, &s1, &c1);
      float twoc = 2.f * c1;
      float sm1 = 0.f, s = s1;
#pragma unroll
      for (int k = 0; k < NR; ++k) {
        rb[k] = sc * s;
        float nxt = fmaf(twoc, s, -sm1);
        sm1 = s; s = nxt;
      }
      float* op = out + (size_t)64000000 + (size_t)u * 7;
#pragma unroll
      for (int k = 0; k < NR; ++k) op[k] = rb[k];
    }
    // threebody RBF, cutoff 4 (output only)
    {
      float x = r * 0.25f;
      float x2 = x * x, x4 = x2 * x2, x8 = x4 * x4;
      float env = fmaf(x8, fmaf(x, fmaf(x, -36.f, 80.f), -45.f), 1.f);
      if (x >= 1.f) env = 0.f;
      float sc = 0.70710678118654752f * env * invr;  // sqrt(2/4)
      float a = PI * x;
      float s1, c1;
      __sincosf(a, &s1, &c1);
      float twoc = 2.f * c1;
      float sm1 = 0.f, s = s1;
      float* op = out + (size_t)67500000 + (size_t)u * 7;
#pragma unroll
      for (int k = 0; k < NR; ++k) {
        op[k] = sc * s;
        float nxt = fmaf(twoc, s, -sm1);
        sm1 = s; s = nxt;
      }
    }
    // LN stats via bilinear forms
    float mu = 0.f;
#pragma unroll
    for (int k = 0; k < NR; ++k) mu = fmaf(rb[k], sQ[49 + k], mu);
    float msq = 0.f;
#pragma unroll
    for (int k = 0; k < NR; ++k) {
      float acc = 0.f;
#pragma unroll
      for (int k2 = 0; k2 < NR; ++k2) acc = fmaf(sQ[k * 7 + k2], rb[k2], acc);
      msq = fmaf(rb[k], acc, msq);
    }
    float var = fmaf(msq, (1.f / 128.f), -mu * mu);
    float rs = rsqrtf(var + 1e-5f);
#pragma unroll
    for (int k = 0; k < NR; ++k) sA[t][k] = rb[k] * rs;
    sA[t][7] = mu * rs;
  } else {
#pragma unroll
    for (int k = 0; k < 8; ++k) sA[t][k] = 0.f;
  }
  __syncthreads();

  // Phase B: 8 edges in flight (one per subgroup g), each lane stores float4.
  const int nv = (NUND - u0 < 256) ? (NUND - u0) : 256;
  for (int eb = 0; eb < 256; eb += 8) {
    int e = eb + g;
    if (e < nv) {
      float4 v0 = *(const float4*)&sA[e][0];
      float4 v1 = *(const float4*)&sA[e][4];
      float4 res;
      float* rp = &res.x;
#pragma unroll
      for (int c = 0; c < 4; ++c) {
        float pre = fmaf(-v1.w, ws4[c], bb4[c]);
        pre = fmaf(v0.x, M4[c][0], pre);
        pre = fmaf(v0.y, M4[c][1], pre);
        pre = fmaf(v0.z, M4[c][2], pre);
        pre = fmaf(v0.w, M4[c][3], pre);
        pre = fmaf(v1.x, M4[c][4], pre);
        pre = fmaf(v1.y, M4[c][5], pre);
        pre = fmaf(v1.z, M4[c][6], pre);
        float sig = 1.f / (1.f + __expf(-pre));
        rp[c] = pre * sig;
      }
      *(float4*)&out[(size_t)(u0 + e) * 128 + 4 * l] = res;
    }
  }
}

extern "C" void kernel_launch(void* const* d_in, const int* in_sizes, int n_in,
                              void* d_out, int out_size, void* d_ws, size_t ws_size,
                              hipStream_t stream) {
  const float* edge_lengths = (const float*)d_in[0];
  const int*   u2d          = (const int*)d_in[1];
  // d_in[2] = directed2undirected — not needed (segment mean of identical rows)
  const float* W1    = (const float*)d_in[3];
  const float* W2    = (const float*)d_in[4];
  const float* gamma = (const float*)d_in[5];
  const float* beta  = (const float*)d_in[6];
  const float* Wsw   = (const float*)d_in[7];
  float* out = (float*)d_out;
  float* ws  = (float*)d_ws;

  hipLaunchKernelGGL(precompute_kernel, dim3(1), dim3(128), 0, stream,
                     W1, W2, gamma, beta, Wsw, ws);
  const int nblk = (NUND + 255) / 256;  // 1954
  hipLaunchKernelGGL(edge_kernel, dim3(nblk), dim3(256), 0, stream,
                     edge_lengths, u2d, ws, out);
}

// Round 3
// 318.973 us; speedup vs baseline: 1.0338x; 1.0338x over previous
//
#include <hip/hip_runtime.h>
#include <math.h>

#define NR 7
#define ED 128
#define NUND 500000
#define PITCH 132  // LDS row pitch for 128-wide staging: 4-float4-aligned, bank-conflict-free

// d_ws float layout:
// [0, 896)     M[d*7+k]   = sum_j gamma[j]*Wsw[d,j]*W12[j,k]
// [896, 1024)  wsum[d]    = sum_j gamma[j]*Wsw[d,j]
// [1024, 1152) bb[d]      = sum_j beta[j]*Wsw[d,j]
// [1152, 1201) Q[k*7+k2]  = sum_j W12[j,k]*W12[j,k2]
// [1201, 1208) m12[k]     = mean_j W12[j,k]

__global__ __launch_bounds__(1024) void precompute_kernel(
    const float* __restrict__ W1, const float* __restrict__ W2,
    const float* __restrict__ gamma, const float* __restrict__ beta,
    const float* __restrict__ Wsw, float* __restrict__ ws)
{
  __shared__ float sBig[ED * PITCH];  // 67.6 KB: W2 then Wsw
  __shared__ float sW1[ED * NR];
  __shared__ float sW12[ED * NR];     // [j][k] = j*7+k
  __shared__ float sGB[2 * ED];
  const int t = threadIdx.x;

  for (int i = t; i < ED * NR; i += 1024) sW1[i] = W1[i];
  if (t < ED) { sGB[t] = gamma[t]; sGB[ED + t] = beta[t]; }
  {
    const float4* src = (const float4*)W2;
    for (int i = t; i < ED * ED / 4; i += 1024) {
      int row = i >> 5, c4 = i & 31;
      *(float4*)&sBig[row * PITCH + 4 * c4] = src[i];
    }
  }
  __syncthreads();

  const int d = t >> 3, k = t & 7;  // 128 rows x 8 lanes (k==7 spare)
  if (k < NR) {
    float acc = 0.f;
    for (int j = 0; j < ED; ++j)
      acc = fmaf(sBig[d * PITCH + j], sW1[j * NR + k], acc);
    sW12[d * NR + k] = acc;
  }
  __syncthreads();  // sW12 complete; sBig-as-W2 no longer needed

  if (t < 49) {
    int a = t / 7, b = t % 7;
    float q = 0.f;
    for (int j = 0; j < ED; ++j) q = fmaf(sW12[j * NR + a], sW12[j * NR + b], q);
    ws[1152 + t] = q;
  } else if (t < 56) {
    int a = t - 49;
    float s = 0.f;
    for (int j = 0; j < ED; ++j) s += sW12[j * NR + a];
    ws[1201 + a] = s * (1.f / 128.f);
  }

  {
    const float4* src = (const float4*)Wsw;
    for (int i = t; i < ED * ED / 4; i += 1024) {
      int row = i >> 5, c4 = i & 31;
      *(float4*)&sBig[row * PITCH + 4 * c4] = src[i];
    }
  }
  __syncthreads();  // sBig now Wsw

  if (k < NR) {
    float m = 0.f;
    for (int j = 0; j < ED; ++j)
      m = fmaf(sGB[j] * sBig[d * PITCH + j], sW12[j * NR + k], m);
    ws[d * NR + k] = m;
  } else {
    float wsum = 0.f, bb = 0.f;
    for (int j = 0; j < ED; ++j) {
      float wv = sBig[d * PITCH + j];
      wsum = fmaf(wv, sGB[j], wsum);
      bb   = fmaf(wv, sGB[ED + j], bb);
    }
    ws[896 + d] = wsum;
    ws[1024 + d] = bb;
  }
}

__global__ __launch_bounds__(256) void edge_kernel(
    const float* __restrict__ el, const int* __restrict__ u2d,
    const float* __restrict__ ws, float* __restrict__ out)
{
  __shared__ float sQ[56];      // Q[49] then m12[7]
  __shared__ float sA[256][8];  // raw rb, later rb*rs [7] + mu*rs
  __shared__ float sB[256][8];  // raw rb3 (threebody output)
  const int t = threadIdx.x;

  if (t < 56) sQ[t] = ws[1152 + t];

  // Phase-B weights: lane group of 32 covers all 128 features, 4 each.
  const int l = t & 31;
  const int g = t >> 5;
  float M4[4][NR], ws4[4], bb4[4];
#pragma unroll
  for (int c = 0; c < 4; ++c) {
    int d = 4 * l + c;
#pragma unroll
    for (int k = 0; k < NR; ++k) M4[c][k] = ws[d * NR + k];
    ws4[c] = ws[896 + d];
    bb4[c] = ws[1024 + d];
  }

  const int u0 = blockIdx.x * 256;
  const int u  = u0 + t;
  const int nv = (NUND - u0 < 256) ? (NUND - u0) : 256;
  __syncthreads();  // sQ ready

  float rs = 0.f, mu = 0.f;
  float rb[NR];
  if (u < NUND) {
    const float r = el[u2d[u]];
    const float invr = 1.f / r;
    const float PI = 3.14159265358979323846f;

    // pairwise RBF, cutoff 6 (raw values -> sA)
    {
      float x = r * (1.f / 6.f);
      float x2 = x * x, x4 = x2 * x2, x8 = x4 * x4;
      float env = fmaf(x8, fmaf(x, fmaf(x, -36.f, 80.f), -45.f), 1.f);
      if (x >= 1.f) env = 0.f;
      float sc = 0.57735026918962576f * env * invr;  // sqrt(2/6)
      float a = PI * x;
      float s1, c1;
      __sincosf(a, &s1, &c1);
      float twoc = 2.f * c1;
      float sm1 = 0.f, s = s1;
#pragma unroll
      for (int k = 0; k < NR; ++k) {
        rb[k] = sc * s;
        sA[t][k] = rb[k];
        float nxt = fmaf(twoc, s, -sm1);
        sm1 = s; s = nxt;
      }
    }
    // threebody RBF, cutoff 4 (raw values -> sB)
    {
      float x = r * 0.25f;
      float x2 = x * x, x4 = x2 * x2, x8 = x4 * x4;
      float env = fmaf(x8, fmaf(x, fmaf(x, -36.f, 80.f), -45.f), 1.f);
      if (x >= 1.f) env = 0.f;
      float sc = 0.70710678118654752f * env * invr;  // sqrt(2/4)
      float a = PI * x;
      float s1, c1;
      __sincosf(a, &s1, &c1);
      float twoc = 2.f * c1;
      float sm1 = 0.f, s = s1;
#pragma unroll
      for (int k = 0; k < NR; ++k) {
        sB[t][k] = sc * s;
        float nxt = fmaf(twoc, s, -sm1);
        sm1 = s; s = nxt;
      }
    }
    // LN stats via bilinear forms
#pragma unroll
    for (int k = 0; k < NR; ++k) mu = fmaf(rb[k], sQ[49 + k], mu);
    float msq = 0.f;
#pragma unroll
    for (int k = 0; k < NR; ++k) {
      float acc = 0.f;
#pragma unroll
      for (int k2 = 0; k2 < NR; ++k2) acc = fmaf(sQ[k * 7 + k2], rb[k2], acc);
      msq = fmaf(rb[k], acc, msq);
    }
    float var = fmaf(msq, (1.f / 128.f), -mu * mu);
    rs = rsqrtf(var + 1e-5f);
  }
  __syncthreads();  // sA/sB raw values ready

  // Coalesced RBF stores: both [nv x 7] blocks are contiguous in memory.
  {
    float* outP = out + (size_t)64000000 + (size_t)u0 * 7;
    float* outT = out + (size_t)67500000 + (size_t)u0 * 7;
    const int total = nv * 7;
    for (int s = t; s < total; s += 256) {
      int e = s / 7, c = s - 7 * e;
      outP[s] = sA[e][c];
      outT[s] = sB[e][c];
    }
  }
  __syncthreads();  // all store-phase reads of sA done

  if (u < NUND) {
#pragma unroll
    for (int k = 0; k < NR; ++k) sA[t][k] = rb[k] * rs;
    sA[t][7] = mu * rs;
  }
  __syncthreads();

  // Phase B: 8 edges in flight (one per subgroup g), each lane stores float4.
  for (int eb = 0; eb < 256; eb += 8) {
    int e = eb + g;
    if (e < nv) {
      float4 v0 = *(const float4*)&sA[e][0];
      float4 v1 = *(const float4*)&sA[e][4];
      float4 res;
      float* rp = &res.x;
#pragma unroll
      for (int c = 0; c < 4; ++c) {
        float pre = fmaf(-v1.w, ws4[c], bb4[c]);
        pre = fmaf(v0.x, M4[c][0], pre);
        pre = fmaf(v0.y, M4[c][1], pre);
        pre = fmaf(v0.z, M4[c][2], pre);
        pre = fmaf(v0.w, M4[c][3], pre);
        pre = fmaf(v1.x, M4[c][4], pre);
        pre = fmaf(v1.y, M4[c][5], pre);
        pre = fmaf(v1.z, M4[c][6], pre);
        float sig = 1.f / (1.f + __expf(-pre));
        rp[c] = pre * sig;
      }
      *(float4*)&out[(size_t)(u0 + e) * 128 + 4 * l] = res;
    }
  }
}

extern "C" void kernel_launch(void* const* d_in, const int* in_sizes, int n_in,
                              void* d_out, int out_size, void* d_ws, size_t ws_size,
                              hipStream_t stream) {
  const float* edge_lengths = (const float*)d_in[0];
  const int*   u2d          = (const int*)d_in[1];
  // d_in[2] = directed2undirected — not needed (segment mean of identical rows)
  const float* W1    = (const float*)d_in[3];
  const float* W2    = (const float*)d_in[4];
  const float* gamma = (const float*)d_in[5];
  const float* beta  = (const float*)d_in[6];
  const float* Wsw   = (const float*)d_in[7];
  float* out = (float*)d_out;
  float* ws  = (float*)d_ws;

  hipLaunchKernelGGL(precompute_kernel, dim3(1), dim3(1024), 0, stream,
                     W1, W2, gamma, beta, Wsw, ws);
  const int nblk = (NUND + 255) / 256;  // 1954
  hipLaunchKernelGGL(edge_kernel, dim3(nblk), dim3(256), 0, stream,
                     edge_lengths, u2d, ws, out);
}